// Round 10
// baseline (177.828 us; speedup 1.0000x reference)
//
#include <hip/hip_runtime.h>
#include <math.h>

// loss = ALPHA * mean(level_w * (softplus(x) - x*t))
//      + BETA  * sum_{b,e} relu(sig(x[b,dst]) - sig(x[b,src])) / (B*N)
// (scatter target of the consistency add is irrelevant to the mean)
//
// R9: two-kernel split (fused structure was lockstep phase-alternating,
// pinned at ~50 us with every pipe <35% busy; R8's in-kernel pipeline
// spilled). K1 = pure streaming: BCE + sigmoid, P written to ws in
// interleaved [B/8][N][8] fp16 layout with contiguous b128 stores.
// K2 = per row-group: memcpy 64 KB group into LDS (node-major already),
// one ds_read_b128 per edge endpoint covers 8 rows.

#define ALPHA_C 1.0f
#define BETA_C  0.5f

constexpr int B = 4096;
constexpr int N = 4096;
constexpr int E = 16384;

typedef _Float16 h8 __attribute__((ext_vector_type(8)));

__global__ __launch_bounds__(64) void init_out_kernel(float* out) {
    if (threadIdx.x == 0) out[0] = 0.0f;
}

__device__ __forceinline__ void fast_sig_sp(float x, float& p, float& sp) {
    // q = exp(-|x|) in (0,1]; both sigmoid and softplus from one exp
    float q = __expf(-fabsf(x));
    float d = 1.0f + q;
    float r = __builtin_amdgcn_rcpf(d);     // ~1 ulp approx reciprocal
    p  = (x >= 0.0f) ? r : q * r;           // sigmoid
    sp = fmaxf(x, 0.0f) + __logf(d);        // softplus = max(x,0)+log(1+q)
}

// ---------------- K1: streaming BCE + sigmoid -> Pint ----------------
constexpr int T1 = 1024;
__global__ __launch_bounds__(T1, 4)
__attribute__((amdgpu_waves_per_eu(4, 4)))   // pin 128-VGPR budget: no spill
void k1_bce_sig(
    const float* __restrict__ outputs,
    const float* __restrict__ targets,
    const float* __restrict__ level_w,
    _Float16*    __restrict__ Pint,          // [B/8][N][8] fp16
    float*       __restrict__ out)
{
    __shared__ float red[16];
    const int g   = blockIdx.x;              // rows 8g .. 8g+7
    const int tid = threadIdx.x;             // node-group: nodes 4tid..4tid+3

    const float4* out4 = (const float4*)outputs;
    const float4* tgt4 = (const float4*)targets;

    // batch ALL 16 payload loads: 16 cache lines in flight per thread
    float4 xs[8], ts[8];
#pragma unroll
    for (int r = 0; r < 8; ++r) {
        const size_t off = (size_t)(8 * g + r) * (N / 4) + tid;
        xs[r] = out4[off];
        ts[r] = tgt4[off];
    }
    const float4 w = ((const float4*)level_w)[tid];
    const float wv[4] = {w.x, w.y, w.z, w.w};

    float s1 = 0.0f;
    h8 pv[4];                               // pv[k][r] = p(row 8g+r, node 4tid+k)
#pragma unroll
    for (int r = 0; r < 8; ++r) {
        const float xv[4] = {xs[r].x, xs[r].y, xs[r].z, xs[r].w};
        const float tv[4] = {ts[r].x, ts[r].y, ts[r].z, ts[r].w};
#pragma unroll
        for (int k = 0; k < 4; ++k) {
            float p, sp;
            fast_sig_sp(xv[k], p, sp);
            s1 = fmaf(wv[k], sp - xv[k] * tv[k], s1);
            pv[k][r] = (_Float16)p;
        }
    }
    // contiguous interleaved store: 4 x b128 per thread, coalesced
    h8* PG = (h8*)(Pint + (size_t)g * (N * 8));
#pragma unroll
    for (int k = 0; k < 4; ++k) PG[4 * tid + k] = pv[k];

    // block reduce s1 -> one atomic
#pragma unroll
    for (int off = 32; off > 0; off >>= 1) s1 += __shfl_down(s1, off, 64);
    const int wave = tid >> 6, lane = tid & 63;
    if (lane == 0) red[wave] = s1;
    __syncthreads();
    if (tid == 0) {
        float a = 0.0f;
#pragma unroll
        for (int i = 0; i < 16; ++i) a += red[i];
        atomicAdd(out, ALPHA_C * a / ((float)B * (float)N));
    }
}

// ---------------- K2: edge consistency over one row-group ----------------
constexpr int T2 = 1024;
__global__ __launch_bounds__(T2, 4) void k2_edges(
    const _Float16* __restrict__ Pint,
    const int*      __restrict__ edge_src,
    const int*      __restrict__ edge_dst,
    float*          __restrict__ out)
{
    __shared__ h8 Pl[N];                    // 64 KB, node-major: Pl[n][r]
    __shared__ float red[16];

    const int g   = blockIdx.x;
    const int tid = threadIdx.x;

    // edge indices first: 8 int4 cached in regs, in flight during LDS fill
    const int4* es4 = (const int4*)edge_src;
    const int4* ed4 = (const int4*)edge_dst;
    int4 sc[4], dc[4];
#pragma unroll
    for (int j = 0; j < 4; ++j) {
        sc[j] = es4[tid + j * T2];
        dc[j] = ed4[tid + j * T2];
    }

    // LDS fill: straight 64 KB copy (layout already node-major interleaved)
    const h8* PG = (const h8*)(Pint + (size_t)g * (N * 8));
#pragma unroll
    for (int j = 0; j < N / T2; ++j)        // 4 x (b128 load + b128 ds_write)
        Pl[tid + j * T2] = PG[tid + j * T2];
    __syncthreads();

    // gather: ONE ds_read_b128 per endpoint covers 8 rows
    float s2 = 0.0f;
    const h8 zero = {0, 0, 0, 0, 0, 0, 0, 0};
#pragma unroll
    for (int j = 0; j < 4; ++j) {
        h8 acc = zero;                      // <=4 edges: fp16-safe magnitude
        h8 a0 = Pl[sc[j].x], c0 = Pl[dc[j].x];
        h8 a1 = Pl[sc[j].y], c1 = Pl[dc[j].y];
        h8 a2 = Pl[sc[j].z], c2 = Pl[dc[j].z];
        h8 a3 = Pl[sc[j].w], c3 = Pl[dc[j].w];
        acc += __builtin_elementwise_max(c0 - a0, zero);    // v_pk_* fp16
        acc += __builtin_elementwise_max(c1 - a1, zero);
        acc += __builtin_elementwise_max(c2 - a2, zero);
        acc += __builtin_elementwise_max(c3 - a3, zero);
#pragma unroll
        for (int l = 0; l < 8; ++l) s2 += (float)acc[l];    // fp32 flush
    }

    // block reduce s2 -> one atomic
#pragma unroll
    for (int off = 32; off > 0; off >>= 1) s2 += __shfl_down(s2, off, 64);
    const int wave = tid >> 6, lane = tid & 63;
    if (lane == 0) red[wave] = s2;
    __syncthreads();
    if (tid == 0) {
        float c = 0.0f;
#pragma unroll
        for (int i = 0; i < 16; ++i) c += red[i];
        atomicAdd(out, BETA_C * c / ((float)B * (float)N));
    }
}

extern "C" void kernel_launch(void* const* d_in, const int* in_sizes, int n_in,
                              void* d_out, int out_size, void* d_ws, size_t ws_size,
                              hipStream_t stream) {
    const float* outputs = (const float*)d_in[0];
    const float* targets = (const float*)d_in[1];
    const float* level_w = (const float*)d_in[2];
    const int*   edge_src = (const int*)d_in[3];
    const int*   edge_dst = (const int*)d_in[4];
    float* out = (float*)d_out;
    _Float16* Pint = (_Float16*)d_ws;       // 32 MB scratch

    init_out_kernel<<<1, 64, 0, stream>>>(out);
    k1_bce_sig<<<B / 8, T1, 0, stream>>>(outputs, targets, level_w, Pint, out);
    k2_edges<<<B / 8, T2, 0, stream>>>(Pint, edge_src, edge_dst, out);
}